// Round 1
// baseline (61.870 us; speedup 1.0000x reference)
//
#include <hip/hip_runtime.h>

// One thread per sample. Each sample: 64 f32 in (16x float4), 4 f32 out (2x float2).
// Memory-bound: ~285 MB total traffic, roofline ~45 us @ 6.3 TB/s.

__global__ __launch_bounds__(256) void convs_mlp_kernel(
    const float* __restrict__ x,
    const float* __restrict__ c1,
    const float* __restrict__ c2,
    const float* __restrict__ W1,
    const float* __restrict__ b1,
    const float* __restrict__ W2,
    const float* __restrict__ b2,
    float* __restrict__ out,
    int B)
{
    int i = blockIdx.x * blockDim.x + threadIdx.x;
    if (i >= B) return;

    // Wave-uniform weight loads -> scalar (s_load) broadcasts, L2-cached.
    const float k00 = c1[0], k01 = c1[1], k10 = c1[2], k11 = c1[3];
    const float m00 = c2[0], m01 = c2[1], m10 = c2[2], m11 = c2[3];
    const float w10 = W1[0], w11 = W1[1], w12 = W1[2],  w13 = W1[3];
    const float w14 = W1[4], w15 = W1[5], w16 = W1[6],  w17 = W1[7];
    const float w18 = W1[8], w19 = W1[9], w1a = W1[10], w1b = W1[11];
    const float bb0 = b1[0], bb1 = b1[1], bb2 = b1[2];
    const float v00 = W2[0], v01 = W2[1], v02 = W2[2];
    const float v10 = W2[3], v11 = W2[4], v12 = W2[5];
    const float c0 = b2[0], c1b = b2[1];

    const float4* __restrict__ xp =
        reinterpret_cast<const float4*>(x + (size_t)i * 64);

    // conv1: 8x8 -> 4x4, 2x2 windows stride 2, then relu(. - 0.2)
    float x1[4][4];
#pragma unroll
    for (int h = 0; h < 4; ++h) {
        // rows 2h and 2h+1, 8 floats each = 2 float4 per row
        float4 r0a = xp[h * 4 + 0];
        float4 r0b = xp[h * 4 + 1];
        float4 r1a = xp[h * 4 + 2];
        float4 r1b = xp[h * 4 + 3];
        x1[h][0] = fmaxf(fmaf(r0a.x, k00, fmaf(r0a.y, k01, fmaf(r1a.x, k10, r1a.y * k11))) - 0.2f, 0.0f);
        x1[h][1] = fmaxf(fmaf(r0a.z, k00, fmaf(r0a.w, k01, fmaf(r1a.z, k10, r1a.w * k11))) - 0.2f, 0.0f);
        x1[h][2] = fmaxf(fmaf(r0b.x, k00, fmaf(r0b.y, k01, fmaf(r1b.x, k10, r1b.y * k11))) - 0.2f, 0.0f);
        x1[h][3] = fmaxf(fmaf(r0b.z, k00, fmaf(r0b.w, k01, fmaf(r1b.z, k10, r1b.w * k11))) - 0.2f, 0.0f);
    }

    // conv2: 4x4 -> 2x2, then f = relu(x2 - 2.0), flat order (h,w)=(0,0),(0,1),(1,0),(1,1)
    float f0 = fmaxf(fmaf(x1[0][0], m00, fmaf(x1[0][1], m01, fmaf(x1[1][0], m10, x1[1][1] * m11))) - 2.0f, 0.0f);
    float f1 = fmaxf(fmaf(x1[0][2], m00, fmaf(x1[0][3], m01, fmaf(x1[1][2], m10, x1[1][3] * m11))) - 2.0f, 0.0f);
    float f2 = fmaxf(fmaf(x1[2][0], m00, fmaf(x1[2][1], m01, fmaf(x1[3][0], m10, x1[3][1] * m11))) - 2.0f, 0.0f);
    float f3 = fmaxf(fmaf(x1[2][2], m00, fmaf(x1[2][3], m01, fmaf(x1[3][2], m10, x1[3][3] * m11))) - 2.0f, 0.0f);

    // h = relu(f @ W1^T + b1), W1 is [3][4] row-major
    float h0 = fmaxf(fmaf(f0, w10, fmaf(f1, w11, fmaf(f2, w12, fmaf(f3, w13, bb0)))), 0.0f);
    float h1 = fmaxf(fmaf(f0, w14, fmaf(f1, w15, fmaf(f2, w16, fmaf(f3, w17, bb1)))), 0.0f);
    float h2 = fmaxf(fmaf(f0, w18, fmaf(f1, w19, fmaf(f2, w1a, fmaf(f3, w1b, bb2)))), 0.0f);

    // raw = h @ W2^T + b2, W2 is [2][3] row-major
    float r0 = fmaf(h0, v00, fmaf(h1, v01, fmaf(h2, v02, c0)));
    float r1 = fmaf(h0, v10, fmaf(h1, v11, fmaf(h2, v12, c1b)));

    // stable 2-way softmax
    float mm = fmaxf(r0, r1);
    float e0 = __expf(r0 - mm);
    float e1 = __expf(r1 - mm);
    float inv = 1.0f / (e0 + e1);

    // outputs: classification [B,2] then raw [B,2], concatenated flat
    reinterpret_cast<float2*>(out)[i] = make_float2(e0 * inv, e1 * inv);
    reinterpret_cast<float2*>(out)[(size_t)B + i] = make_float2(r0, r1);
}

extern "C" void kernel_launch(void* const* d_in, const int* in_sizes, int n_in,
                              void* d_out, int out_size, void* d_ws, size_t ws_size,
                              hipStream_t stream) {
    const float* x  = (const float*)d_in[0];
    const float* c1 = (const float*)d_in[1];
    const float* c2 = (const float*)d_in[2];
    const float* W1 = (const float*)d_in[3];
    const float* b1 = (const float*)d_in[4];
    const float* W2 = (const float*)d_in[5];
    const float* b2 = (const float*)d_in[6];
    float* out = (float*)d_out;

    int B = in_sizes[0] / 64;  // x is [B, 1, 8, 8]
    int block = 256;
    int grid = (B + block - 1) / block;
    convs_mlp_kernel<<<grid, block, 0, stream>>>(x, c1, c2, W1, b1, W2, b2, out, B);
}

// Round 2
// 46.499 us; speedup vs baseline: 1.3306x; 1.3306x over previous
//
#include <hip/hip_runtime.h>

// Block = 256 threads = 256 samples. Stage 64KB to LDS with fully-coalesced
// global loads (1KB contiguous per wave-instruction), XOR-swizzled layout so
// staging writes AND per-sample ds_read_b128 are both conflict-free-baseline.
// Compute per sample entirely in registers (validated in R0).

__global__ __launch_bounds__(256) void convs_mlp_lds(
    const float4* __restrict__ x4,   // [B*16] float4 view of [B,64]
    const float* __restrict__ c1,
    const float* __restrict__ c2,
    const float* __restrict__ W1,
    const float* __restrict__ b1,
    const float* __restrict__ W2,
    const float* __restrict__ b2,
    float* __restrict__ out,
    int B)
{
    __shared__ float4 lds4[4096];  // exactly 64 KB

    const int t = threadIdx.x;                 // 0..255
    const long sblk = (long)blockIdx.x * 256;  // first sample of this block

    // ---- stage: coalesced global -> swizzled LDS ----
    // layout: chunk j' of block-sample ts lives at lds4[16*ts + (j' ^ (ts&15))]
    const float4* __restrict__ gsrc = x4 + sblk * 16;
    const int wslot = (t >> 4) * 16 + ((t & 15) ^ (t >> 4));  // constant per thread
#pragma unroll
    for (int j = 0; j < 16; ++j) {
        // global float4 idx j*256+t = sample (j*16 + t/16), chunk (t&15)
        lds4[j * 256 + wslot] = gsrc[j * 256 + t];
    }
    __syncthreads();

    // ---- wave-uniform weights (s_load broadcasts) ----
    const float k00 = c1[0], k01 = c1[1], k10 = c1[2], k11 = c1[3];
    const float m00 = c2[0], m01 = c2[1], m10 = c2[2], m11 = c2[3];
    const float w10 = W1[0], w11 = W1[1], w12 = W1[2],  w13 = W1[3];
    const float w14 = W1[4], w15 = W1[5], w16 = W1[6],  w17 = W1[7];
    const float w18 = W1[8], w19 = W1[9], w1a = W1[10], w1b = W1[11];
    const float bb0 = b1[0], bb1 = b1[1], bb2 = b1[2];
    const float v00 = W2[0], v01 = W2[1], v02 = W2[2];
    const float v10 = W2[3], v11 = W2[4], v12 = W2[5];
    const float c0 = b2[0], c1b = b2[1];

    // ---- per-sample compute from LDS ----
    const int rb = t * 16;
    const int xr = t & 15;

    // conv1: 8x8 -> 4x4 (2x2 stride-2), relu(. - 0.2)
    float x1[4][4];
#pragma unroll
    for (int h = 0; h < 4; ++h) {
        float4 r0a = lds4[rb + ((4 * h + 0) ^ xr)];  // row 2h,   cols 0..3
        float4 r0b = lds4[rb + ((4 * h + 1) ^ xr)];  // row 2h,   cols 4..7
        float4 r1a = lds4[rb + ((4 * h + 2) ^ xr)];  // row 2h+1, cols 0..3
        float4 r1b = lds4[rb + ((4 * h + 3) ^ xr)];  // row 2h+1, cols 4..7
        x1[h][0] = fmaxf(fmaf(r0a.x, k00, fmaf(r0a.y, k01, fmaf(r1a.x, k10, r1a.y * k11))) - 0.2f, 0.0f);
        x1[h][1] = fmaxf(fmaf(r0a.z, k00, fmaf(r0a.w, k01, fmaf(r1a.z, k10, r1a.w * k11))) - 0.2f, 0.0f);
        x1[h][2] = fmaxf(fmaf(r0b.x, k00, fmaf(r0b.y, k01, fmaf(r1b.x, k10, r1b.y * k11))) - 0.2f, 0.0f);
        x1[h][3] = fmaxf(fmaf(r0b.z, k00, fmaf(r0b.w, k01, fmaf(r1b.z, k10, r1b.w * k11))) - 0.2f, 0.0f);
    }

    // conv2: 4x4 -> 2x2, then f = relu(. - 2.0)
    float f0 = fmaxf(fmaf(x1[0][0], m00, fmaf(x1[0][1], m01, fmaf(x1[1][0], m10, x1[1][1] * m11))) - 2.0f, 0.0f);
    float f1 = fmaxf(fmaf(x1[0][2], m00, fmaf(x1[0][3], m01, fmaf(x1[1][2], m10, x1[1][3] * m11))) - 2.0f, 0.0f);
    float f2 = fmaxf(fmaf(x1[2][0], m00, fmaf(x1[2][1], m01, fmaf(x1[3][0], m10, x1[3][1] * m11))) - 2.0f, 0.0f);
    float f3 = fmaxf(fmaf(x1[2][2], m00, fmaf(x1[2][3], m01, fmaf(x1[3][2], m10, x1[3][3] * m11))) - 2.0f, 0.0f);

    // MLP
    float h0 = fmaxf(fmaf(f0, w10, fmaf(f1, w11, fmaf(f2, w12, fmaf(f3, w13, bb0)))), 0.0f);
    float h1 = fmaxf(fmaf(f0, w14, fmaf(f1, w15, fmaf(f2, w16, fmaf(f3, w17, bb1)))), 0.0f);
    float h2 = fmaxf(fmaf(f0, w18, fmaf(f1, w19, fmaf(f2, w1a, fmaf(f3, w1b, bb2)))), 0.0f);

    float r0 = fmaf(h0, v00, fmaf(h1, v01, fmaf(h2, v02, c0)));
    float r1 = fmaf(h0, v10, fmaf(h1, v11, fmaf(h2, v12, c1b)));

    float mm = fmaxf(r0, r1);
    float e0 = __expf(r0 - mm);
    float e1 = __expf(r1 - mm);
    float inv = 1.0f / (e0 + e1);

    const long s = sblk + t;
    reinterpret_cast<float2*>(out)[s] = make_float2(e0 * inv, e1 * inv);
    reinterpret_cast<float2*>(out)[(long)B + s] = make_float2(r0, r1);
}

// Tail kernel (per-thread direct loads) for B % 256 leftovers — same math.
__global__ __launch_bounds__(256) void convs_mlp_tail(
    const float* __restrict__ x,
    const float* __restrict__ c1,
    const float* __restrict__ c2,
    const float* __restrict__ W1,
    const float* __restrict__ b1,
    const float* __restrict__ W2,
    const float* __restrict__ b2,
    float* __restrict__ out,
    int B, int start)
{
    int i = start + blockIdx.x * blockDim.x + threadIdx.x;
    if (i >= B) return;

    const float k00 = c1[0], k01 = c1[1], k10 = c1[2], k11 = c1[3];
    const float m00 = c2[0], m01 = c2[1], m10 = c2[2], m11 = c2[3];
    const float w10 = W1[0], w11 = W1[1], w12 = W1[2],  w13 = W1[3];
    const float w14 = W1[4], w15 = W1[5], w16 = W1[6],  w17 = W1[7];
    const float w18 = W1[8], w19 = W1[9], w1a = W1[10], w1b = W1[11];
    const float bb0 = b1[0], bb1 = b1[1], bb2 = b1[2];
    const float v00 = W2[0], v01 = W2[1], v02 = W2[2];
    const float v10 = W2[3], v11 = W2[4], v12 = W2[5];
    const float c0 = b2[0], c1b = b2[1];

    const float4* __restrict__ xp = reinterpret_cast<const float4*>(x + (size_t)i * 64);

    float x1[4][4];
#pragma unroll
    for (int h = 0; h < 4; ++h) {
        float4 r0a = xp[h * 4 + 0];
        float4 r0b = xp[h * 4 + 1];
        float4 r1a = xp[h * 4 + 2];
        float4 r1b = xp[h * 4 + 3];
        x1[h][0] = fmaxf(fmaf(r0a.x, k00, fmaf(r0a.y, k01, fmaf(r1a.x, k10, r1a.y * k11))) - 0.2f, 0.0f);
        x1[h][1] = fmaxf(fmaf(r0a.z, k00, fmaf(r0a.w, k01, fmaf(r1a.z, k10, r1a.w * k11))) - 0.2f, 0.0f);
        x1[h][2] = fmaxf(fmaf(r0b.x, k00, fmaf(r0b.y, k01, fmaf(r1b.x, k10, r1b.y * k11))) - 0.2f, 0.0f);
        x1[h][3] = fmaxf(fmaf(r0b.z, k00, fmaf(r0b.w, k01, fmaf(r1b.z, k10, r1b.w * k11))) - 0.2f, 0.0f);
    }

    float f0 = fmaxf(fmaf(x1[0][0], m00, fmaf(x1[0][1], m01, fmaf(x1[1][0], m10, x1[1][1] * m11))) - 2.0f, 0.0f);
    float f1 = fmaxf(fmaf(x1[0][2], m00, fmaf(x1[0][3], m01, fmaf(x1[1][2], m10, x1[1][3] * m11))) - 2.0f, 0.0f);
    float f2 = fmaxf(fmaf(x1[2][0], m00, fmaf(x1[2][1], m01, fmaf(x1[3][0], m10, x1[3][1] * m11))) - 2.0f, 0.0f);
    float f3 = fmaxf(fmaf(x1[2][2], m00, fmaf(x1[2][3], m01, fmaf(x1[3][2], m10, x1[3][3] * m11))) - 2.0f, 0.0f);

    float h0 = fmaxf(fmaf(f0, w10, fmaf(f1, w11, fmaf(f2, w12, fmaf(f3, w13, bb0)))), 0.0f);
    float h1 = fmaxf(fmaf(f0, w14, fmaf(f1, w15, fmaf(f2, w16, fmaf(f3, w17, bb1)))), 0.0f);
    float h2 = fmaxf(fmaf(f0, w18, fmaf(f1, w19, fmaf(f2, w1a, fmaf(f3, w1b, bb2)))), 0.0f);

    float r0 = fmaf(h0, v00, fmaf(h1, v01, fmaf(h2, v02, c0)));
    float r1 = fmaf(h0, v10, fmaf(h1, v11, fmaf(h2, v12, c1b)));

    float mm = fmaxf(r0, r1);
    float e0 = __expf(r0 - mm);
    float e1 = __expf(r1 - mm);
    float inv = 1.0f / (e0 + e1);

    reinterpret_cast<float2*>(out)[i] = make_float2(e0 * inv, e1 * inv);
    reinterpret_cast<float2*>(out)[(size_t)B + i] = make_float2(r0, r1);
}

extern "C" void kernel_launch(void* const* d_in, const int* in_sizes, int n_in,
                              void* d_out, int out_size, void* d_ws, size_t ws_size,
                              hipStream_t stream) {
    const float* x  = (const float*)d_in[0];
    const float* c1 = (const float*)d_in[1];
    const float* c2 = (const float*)d_in[2];
    const float* W1 = (const float*)d_in[3];
    const float* b1 = (const float*)d_in[4];
    const float* W2 = (const float*)d_in[5];
    const float* b2 = (const float*)d_in[6];
    float* out = (float*)d_out;

    int B = in_sizes[0] / 64;     // x is [B, 1, 8, 8]
    int fullBlocks = B / 256;
    int rem = B - fullBlocks * 256;

    if (fullBlocks > 0) {
        convs_mlp_lds<<<fullBlocks, 256, 0, stream>>>(
            reinterpret_cast<const float4*>(x), c1, c2, W1, b1, W2, b2, out, B);
    }
    if (rem > 0) {
        convs_mlp_tail<<<(rem + 255) / 256, 256, 0, stream>>>(
            x, c1, c2, W1, b1, W2, b2, out, B, fullBlocks * 256);
    }
}